// Round 6
// baseline (484.603 us; speedup 1.0000x reference)
//
#include <hip/hip_runtime.h>
#include <math.h>

#define F_MH 4
#define NB   512
#define SEQ  2048
#define TOPK 128
#define EDIM 64
#define ADIM 128
#define VOH  10001
#define VMH  100001
#define NROWS (F_MH * VMH)   // 400004
#define D0   1728
#define RSQRT32 0.17677669529663687f

typedef __bf16 bf16x8 __attribute__((ext_vector_type(8)));
typedef __bf16 bf16x4 __attribute__((ext_vector_type(4)));
typedef float  f32x4  __attribute__((ext_vector_type(4)));

// ---------------------------------------------------------------------------
// K1 (R5): LSH signatures. R4 pipeline + hw staged in LDS (broadcast
// ds_read_b128 instead of latency-bound uniform global loads).
// ---------------------------------------------------------------------------
__global__ __launch_bounds__(128) void k_hash(const float* __restrict__ tab,
                                              const float* __restrict__ hw,
                                              unsigned int* __restrict__ sig)
{
    __shared__ float rows[128][65];       // pitch 65: all accesses <=2-way
    __shared__ float4 hwl[512];           // hwl[e*8+h] = hw cols h*4..+3 of elem e
    const int t = threadIdx.x;
    // stage hw (8 KB) once
#pragma unroll
    for (int i = 0; i < 4; ++i) hwl[t + i * 128] = ((const float4*)hw)[t + i * 128];
    const long long base_dw = (long long)blockIdx.x * 32768;   // 512 rows * 64
    const long long lim = (long long)NROWS * 64;
    float4 pf[16];
#pragma unroll
    for (int i = 0; i < 16; ++i) {
        const long long idx = base_dw + i * 512 + t * 4;
        pf[i] = make_float4(0.f, 0.f, 0.f, 0.f);
        if (idx < lim) pf[i] = *(const float4*)(tab + idx);
    }
    for (int c = 0; c < 4; ++c) {
        __syncthreads();              // prior chunk's LDS reads done (also hwl)
#pragma unroll
        for (int i = 0; i < 16; ++i) {
            const int idx = i * 512 + t * 4;
            const int row = idx >> 6, e = idx & 63;
            rows[row][e + 0] = pf[i].x; rows[row][e + 1] = pf[i].y;
            rows[row][e + 2] = pf[i].z; rows[row][e + 3] = pf[i].w;
        }
        __syncthreads();
        if (c < 3) {                  // prefetch next chunk under compute
#pragma unroll
            for (int i = 0; i < 16; ++i) {
                const long long idx = base_dw + (long long)(c + 1) * 8192 + i * 512 + t * 4;
                pf[i] = make_float4(0.f, 0.f, 0.f, 0.f);
                if (idx < lim) pf[i] = *(const float4*)(tab + idx);
            }
        }
        float4 acc[8];
#pragma unroll
        for (int h = 0; h < 8; ++h) acc[h] = make_float4(0.f, 0.f, 0.f, 0.f);
#pragma unroll 8
        for (int e = 0; e < 64; ++e) {
            const float x = rows[t][e];
#pragma unroll
            for (int h = 0; h < 8; ++h) {
                const float4 w = hwl[e * 8 + h];    // broadcast ds_read_b128
                acc[h].x += x * w.x; acc[h].y += x * w.y;
                acc[h].z += x * w.z; acc[h].w += x * w.w;
            }
        }
        unsigned int bits = 0u;
#pragma unroll
        for (int h = 0; h < 8; ++h) {
            bits |= (acc[h].x > 0.f ? 1u : 0u) << (h * 4);
            bits |= (acc[h].y > 0.f ? 2u : 0u) << (h * 4);
            bits |= (acc[h].z > 0.f ? 4u : 0u) << (h * 4);
            bits |= (acc[h].w > 0.f ? 8u : 0u) << (h * 4);
        }
        const int r = blockIdx.x * 512 + c * 128 + t;
        if (r < NROWS) sig[r] = bits;
    }
}

// ---------------------------------------------------------------------------
// K2: per-(f,b) top-K=128 by Hamming distance (histogram + stable tie pick).
// ---------------------------------------------------------------------------
__global__ __launch_bounds__(256) void k_topk(const float* __restrict__ oh_tab,
                                              const float* __restrict__ hw,
                                              const unsigned int* __restrict__ sig,
                                              const int* __restrict__ oh_ids,
                                              const int* __restrict__ mh_ids,
                                              int* __restrict__ sel)
{
    const int b = blockIdx.x, f = blockIdx.y, t = threadIdx.x;
    __shared__ float tgt[64];
    __shared__ unsigned int thbits;
    __shared__ int hist[34];
    __shared__ int c_lt[256], c_eq[256];
    __shared__ int s_dstar, s_cntlt;
    if (t < 64) tgt[t] = oh_tab[((size_t)f * VOH + oh_ids[b * 15 + f]) * 64 + t];
    if (t == 0) thbits = 0u;
    if (t < 34) hist[t] = 0;
    __syncthreads();
    if (t < 32) {
        float acc = 0.f;
#pragma unroll
        for (int e = 0; e < 64; ++e) acc += tgt[e] * hw[e * 32 + t];
        if (acc > 0.f) atomicOr(&thbits, 1u << t);
    }
    __syncthreads();
    const unsigned int th = thbits;
    const int* idp = mh_ids + (size_t)(f * NB + b) * SEQ + t * 8;
    int ids[8], dv[8];
#pragma unroll
    for (int j = 0; j < 8; ++j) {
        int id = idp[j];
        ids[j] = id;
        int d = (id >= 0) ? __popc(sig[f * VMH + id] ^ th) : 33;
        dv[j] = d;
        atomicAdd(&hist[d], 1);
    }
    __syncthreads();
    if (t == 0) {
        int cum = 0, ds = 33, cl = 0;
        for (int d = 0; d <= 33; ++d) {
            if (cum + hist[d] >= TOPK) { ds = d; cl = cum; break; }
            cum += hist[d];
        }
        s_dstar = ds; s_cntlt = cl;
    }
    __syncthreads();
    const int Dstar = s_dstar, cntlt = s_cntlt;
    int nlt = 0, neq = 0;
#pragma unroll
    for (int j = 0; j < 8; ++j) {
        nlt += (dv[j] < Dstar);
        neq += (dv[j] == Dstar);
    }
    c_lt[t] = nlt; c_eq[t] = neq;
    __syncthreads();
    for (int off = 1; off < 256; off <<= 1) {
        int vl = 0, ve = 0;
        if (t >= off) { vl = c_lt[t - off]; ve = c_eq[t - off]; }
        __syncthreads();
        c_lt[t] += vl; c_eq[t] += ve;
        __syncthreads();
    }
    int lt_pos = c_lt[t] - nlt;
    int eq_pos = cntlt + c_eq[t] - neq;
    int* selp = sel + (size_t)(f * NB + b) * TOPK;
#pragma unroll
    for (int j = 0; j < 8; ++j) {
        if (dv[j] < Dstar) { selp[lt_pos++] = ids[j]; }
        else if (dv[j] == Dstar) {
            if (eq_pos < TOPK) selp[eq_pos] = ids[j];
            eq_pos++;
        }
    }
}

// ---------------------------------------------------------------------------
// K_fold: precompute folded attention weights per (z,f,h):
//   Mq[e'][e] = sum_d WQ[e'][h,d]*WK[e][h,d]
//   B1[e]     = sum_d bq[h,d]  *WK[e][h,d]
//   VO[e][o]  = sum_d WV[e][h,d]*WO[h*32+d][o]
//   bvo[o]    = sum_a bv[a]*WO[a][o] + bo[o]        (h==0 block only)
// The per-head scalar q.bk shifts scores uniformly -> cancels in softmax.
// ---------------------------------------------------------------------------
__global__ __launch_bounds__(256) void k_fold(const float* __restrict__ sqW, const float* __restrict__ sqb,
                                              const float* __restrict__ skW,
                                              const float* __restrict__ svW, const float* __restrict__ svb,
                                              const float* __restrict__ soW, const float* __restrict__ sob,
                                              const float* __restrict__ lqW, const float* __restrict__ lqb,
                                              const float* __restrict__ lkW,
                                              const float* __restrict__ lvW, const float* __restrict__ lvb,
                                              const float* __restrict__ loW, const float* __restrict__ lob,
                                              float* __restrict__ Mq, float* __restrict__ B1,
                                              float* __restrict__ VO, float* __restrict__ bvo)
{
    const int f = blockIdx.x, z = blockIdx.y, h = blockIdx.z, t = threadIdx.x;
    const float* WQ = (z ? lqW : sqW) + (size_t)f * 8192;
    const float* bq = (z ? lqb : sqb) + f * 128;
    const float* WK = (z ? lkW : skW) + (size_t)f * 8192;
    const float* WV = (z ? lvW : svW) + (size_t)f * 8192;
    const float* bv = (z ? lvb : svb) + f * 128;
    const float* WO = (z ? loW : soW) + (size_t)f * 8192;
    const float* bo = (z ? lob : sob) + f * 64;

    __shared__ float wq[64][33], wk[64][33], wv[64][33], wo[32][65];
#pragma unroll
    for (int i = 0; i < 8; ++i) {
        int j = t + i * 256;                       // 0..2047
        wq[j >> 5][j & 31] = WQ[(j >> 5) * 128 + h * 32 + (j & 31)];
        wk[j >> 5][j & 31] = WK[(j >> 5) * 128 + h * 32 + (j & 31)];
        wv[j >> 5][j & 31] = WV[(j >> 5) * 128 + h * 32 + (j & 31)];
        wo[j >> 6][j & 63] = WO[(h * 32 + (j >> 6)) * 64 + (j & 63)];
    }
    __syncthreads();
    const int lane = t & 63, grp = t >> 6;
    float* Mqb = Mq + (size_t)(((z * 4 + f) * 4 + h)) * 4096;
    float* VOb = VO + (size_t)(((z * 4 + f) * 4 + h)) * 4096;
#pragma unroll 4
    for (int g = 0; g < 16; ++g) {
        const int ep = grp * 16 + g;
        float am = 0.f, av = 0.f;
#pragma unroll
        for (int d = 0; d < 32; ++d) {
            am += wq[ep][d] * wk[lane][d];
            av += wv[ep][d] * wo[d][lane];
        }
        Mqb[ep * 64 + lane] = am;
        VOb[ep * 64 + lane] = av;
    }
    if (t < 64) {
        float acc = 0.f;
#pragma unroll
        for (int d = 0; d < 32; ++d) acc += bq[h * 32 + d] * wk[t][d];
        B1[((z * 4 + f) * 4 + h) * 64 + t] = acc;
    }
    if (h == 0 && t >= 64 && t < 128) {
        const int o = t - 64;
        float acc = bo[o];
        for (int a = 0; a < 128; ++a) acc += bv[a] * WO[a * 64 + o];
        bvo[(z * 4 + f) * 64 + o] = acc;
    }
}

// ---------------------------------------------------------------------------
// K3 (R5 rewrite): single-query attention via folded weights.
// Per block (b,f,z): gather seq (LDS pitch 65, conflict-free), qk = tgt@Mq
// (coalesced L2 reads), scores+softmax, wemb, out = wemb@VO (coalesced).
// 4 barriers; no uncoalesced weight reads; writes bf16 into feats.
// ---------------------------------------------------------------------------
__global__ __launch_bounds__(256, 4) void k_attn(const float* __restrict__ oh_tab,
                                                 const float* __restrict__ mh_tab,
                                                 const int* __restrict__ oh_ids,
                                                 const int* __restrict__ mh_ids,
                                                 const int* __restrict__ sel,
                                                 const float* __restrict__ Mq,
                                                 const float* __restrict__ B1,
                                                 const float* __restrict__ VO,
                                                 const float* __restrict__ bvo,
                                                 __bf16* __restrict__ feats)
{
    const int b = blockIdx.x, f = blockIdx.y, z = blockIdx.z, t = threadIdx.x;
    const int zf = z * 4 + f;
    const float* Mqb = Mq + (size_t)zf * 4 * 4096;
    const float* B1b = B1 + zf * 4 * 64;
    const float* VOb = VO + (size_t)zf * 4 * 4096;
    const float* bvob = bvo + zf * 64;

    __shared__ float seq[128][65];    // pitch 65 -> conflict-free both phases
    __shared__ float tgt[64];
    __shared__ int   sid[128];
    __shared__ float qk[4][64];
    __shared__ float sc[4][128];
    __shared__ float wemb[4][64];
    __shared__ float partial[4][64];

    if (t < 64) tgt[t] = oh_tab[((size_t)f * VOH + oh_ids[b * 15 + f]) * 64 + t];
    if (t < 128) {
        int id;
        if (z == 0) id = mh_ids[(size_t)(f * NB + b) * SEQ + t];
        else        id = sel[(size_t)(f * NB + b) * TOPK + t];
        sid[t] = id;
    }
    __syncthreads();
    // issue gather loads (held in regs through qk compute)
    float4 ev[2];
#pragma unroll
    for (int i = 0; i < 2; ++i) {
        const int v = t + i * 256;
        const int row = v >> 1, c4 = (v & 1) << 5;   // 2 lanes/row, 32 dwords each? no:
        (void)row; (void)c4;
    }
    // (layout: 16 lanes per row, float4 each -> v>>4 rows, (v&15)*4 cols)
#pragma unroll
    for (int i = 0; i < 2; ++i) {
        const int v = t + i * 256;
        const int row = v >> 2, c4 = (v & 3) << 4;   // 4 lanes/row? ALSO wrong; use 8 float4/thread
        (void)row; (void)c4;
    }
    float4 g[8];
#pragma unroll
    for (int i = 0; i < 8; ++i) {
        const int v = t + i * 256;                   // 0..2047
        const int row = v >> 4, c4 = (v & 15) << 2;
        const int id = sid[row];
        g[i] = make_float4(0.f, 0.f, 0.f, 0.f);
        if (id >= 0) g[i] = *(const float4*)&mh_tab[((size_t)f * VMH + id) * 64 + c4];
    }
    // qk[h][e] = (B1 + sum_e' tgt[e'] * Mq[h][e'][e]) * rsqrt(32)
    {
        const int h = t >> 6, e = t & 63;
        float acc = B1b[h * 64 + e];
        const float* mrow = Mqb + h * 4096 + e;
#pragma unroll 16
        for (int ep = 0; ep < 64; ++ep) acc += tgt[ep] * mrow[ep * 64];
        qk[h][e] = acc * RSQRT32;
    }
    // stage gathered seq
#pragma unroll
    for (int i = 0; i < 8; ++i) {
        const int v = t + i * 256;
        const int row = v >> 4, c4 = (v & 15) << 2;
        seq[row][c4 + 0] = g[i].x; seq[row][c4 + 1] = g[i].y;
        seq[row][c4 + 2] = g[i].z; seq[row][c4 + 3] = g[i].w;
    }
    __syncthreads();
    // scores
#pragma unroll
    for (int rep = 0; rep < 2; ++rep) {
        const int idx = t + rep * 256;
        const int h = idx >> 7, s = idx & 127;
        float acc = 0.f;
#pragma unroll
        for (int e4 = 0; e4 < 16; ++e4) {
            const float4 q4 = *(const float4*)&qk[h][e4 * 4];
            acc += seq[s][e4 * 4 + 0] * q4.x + seq[s][e4 * 4 + 1] * q4.y
                 + seq[s][e4 * 4 + 2] * q4.z + seq[s][e4 * 4 + 3] * q4.w;
        }
        sc[h][s] = (sid[s] >= 0) ? acc : -INFINITY;
    }
    __syncthreads();
    // softmax: wave w handles head h=w (wave-local from here to final)
    {
        const int h = t >> 6, l = t & 63;
        float v0 = sc[h][l], v1 = sc[h][l + 64];
        float m = fmaxf(v0, v1);
        for (int off = 32; off; off >>= 1) m = fmaxf(m, __shfl_xor(m, off));
        float p0 = expf(v0 - m), p1 = expf(v1 - m);
        float ssum = p0 + p1;
        for (int off = 32; off; off >>= 1) ssum += __shfl_xor(ssum, off);
        float inv = 1.f / ssum;
        sc[h][l] = p0 * inv; sc[h][l + 64] = p1 * inv;
    }
    // wemb[h][e] = sum_s attn[h][s] * seq[s][e]   (h = own wave -> no barrier)
    {
        const int h = t >> 6, e = t & 63;
        float acc = 0.f;
#pragma unroll 8
        for (int s4 = 0; s4 < 32; ++s4) {
            const float4 a4 = *(const float4*)&sc[h][s4 * 4];
            acc += a4.x * seq[s4 * 4 + 0][e] + a4.y * seq[s4 * 4 + 1][e]
                 + a4.z * seq[s4 * 4 + 2][e] + a4.w * seq[s4 * 4 + 3][e];
        }
        wemb[h][e] = acc;
    }
    // partial[h][o] = sum_e wemb[h][e] * VO[h][e][o]   (own wave's wemb)
    {
        const int h = t >> 6, o = t & 63;
        float acc = 0.f;
        const float* vrow = VOb + h * 4096 + o;
#pragma unroll 16
        for (int e = 0; e < 64; ++e) acc += wemb[h][e] * vrow[e * 64];
        partial[h][o] = acc;
    }
    __syncthreads();
    if (t < 64) {
        float acc = partial[0][t] + partial[1][t] + partial[2][t] + partial[3][t] + bvob[t];
        feats[(size_t)b * D0 + (z ? 1472 : 1216) + f * 64 + t] = (__bf16)acc;
    }
}

// ---------------------------------------------------------------------------
// K4: feats assembly (bf16 output)
// ---------------------------------------------------------------------------
__global__ __launch_bounds__(256) void k_feats(const float* __restrict__ oh_tab,
                                               const float* __restrict__ sp_tab,
                                               const int* __restrict__ oh_ids,
                                               const int* __restrict__ sp_ids,
                                               __bf16* __restrict__ feats)
{
    const int b = blockIdx.x, t = threadIdx.x;
    __shared__ int sidl[200];
    __shared__ int ohid[15];
    if (t < 200) sidl[t] = sp_ids[(size_t)((t / 50) * NB + b) * 50 + (t % 50)];
    if (t >= 240 && t < 255) ohid[t - 240] = oh_ids[b * 15 + (t - 240)];
    __syncthreads();
    __bf16* fr = feats + (size_t)b * D0;
    for (int p = t; p < 960; p += 256) {
        int f = p >> 6, e = p & 63;
        fr[p] = (__bf16)oh_tab[((size_t)f * VOH + ohid[f]) * 64 + e];
    }
    {
        int f = t >> 6, e = t & 63;
        float acc = 0.f;
        for (int j = 0; j < 50; ++j) {
            int id = sidl[f * 50 + j];
            if (id >= 0) acc += sp_tab[((size_t)f * VOH + id) * 64 + e];
        }
        fr[960 + t] = (__bf16)acc;
    }
}

// ---------------------------------------------------------------------------
// K5a: weight transpose+convert: W f32 [K][N] -> WT bf16 [N][K]
// ---------------------------------------------------------------------------
__global__ __launch_bounds__(256) void k_trans(const float* __restrict__ W,
                                               __bf16* __restrict__ WT,
                                               int K, int N)
{
    __shared__ float tile[32][33];
    const int t = threadIdx.x;
    const int n0 = blockIdx.x * 32, k0 = blockIdx.y * 32;
    const int c = t & 31, r = t >> 5;
#pragma unroll
    for (int i = 0; i < 4; ++i)
        tile[r + 8 * i][c] = W[(size_t)(k0 + r + 8 * i) * N + n0 + c];
    __syncthreads();
#pragma unroll
    for (int i = 0; i < 4; ++i)
        WT[(size_t)(n0 + r + 8 * i) * K + k0 + c] = (__bf16)tile[c][r + 8 * i];
}

// ---------------------------------------------------------------------------
// K5b: bf16 MFMA GEMM. A [M,K] bf16 rm, BT [N,K] bf16 rm (pre-transposed),
// C = act(A@B + bias) as bf16 [M,N]. 64x64 tile, 4 waves = 2x2 of 32x32.
// ---------------------------------------------------------------------------
__global__ __launch_bounds__(256) void gemm_mfma(const __bf16* __restrict__ A,
                                                 const __bf16* __restrict__ BT,
                                                 const float* __restrict__ bias,
                                                 __bf16* __restrict__ C,
                                                 int M, int N, int K, int relu)
{
    __shared__ __bf16 As[64][72];
    __shared__ __bf16 Bs[64][72];
    const int t = threadIdx.x;
    const int n0 = blockIdx.x * 64, m0 = blockIdx.y * 64;
    const int wave = t >> 6, lane = t & 63;
    const int wm = (wave >> 1) * 32, wn = (wave & 1) * 32;
    const int row16 = lane & 15, quad = lane >> 4;
    f32x4 acc[2][2] = {};
    const int sr = t >> 3;
    const int sseg = (t & 7) * 8;
    for (int k0 = 0; k0 < K; k0 += 64) {
        bf16x8 av0 = *(const bf16x8*)&A[(size_t)(m0 + sr) * K + k0 + sseg];
        bf16x8 av1 = *(const bf16x8*)&A[(size_t)(m0 + sr + 32) * K + k0 + sseg];
        bf16x8 bv0 = *(const bf16x8*)&BT[(size_t)(n0 + sr) * K + k0 + sseg];
        bf16x8 bv1 = *(const bf16x8*)&BT[(size_t)(n0 + sr + 32) * K + k0 + sseg];
        __syncthreads();
        *(bf16x8*)&As[sr][sseg] = av0;
        *(bf16x8*)&As[sr + 32][sseg] = av1;
        *(bf16x8*)&Bs[sr][sseg] = bv0;
        *(bf16x8*)&Bs[sr + 32][sseg] = bv1;
        __syncthreads();
#pragma unroll
        for (int kk = 0; kk < 2; ++kk) {
            bf16x8 a0 = *(const bf16x8*)&As[wm + row16][kk * 32 + quad * 8];
            bf16x8 a1 = *(const bf16x8*)&As[wm + 16 + row16][kk * 32 + quad * 8];
            bf16x8 b0 = *(const bf16x8*)&Bs[wn + row16][kk * 32 + quad * 8];
            bf16x8 b1 = *(const bf16x8*)&Bs[wn + 16 + row16][kk * 32 + quad * 8];
            acc[0][0] = __builtin_amdgcn_mfma_f32_16x16x32_bf16(a0, b0, acc[0][0], 0, 0, 0);
            acc[0][1] = __builtin_amdgcn_mfma_f32_16x16x32_bf16(a0, b1, acc[0][1], 0, 0, 0);
            acc[1][0] = __builtin_amdgcn_mfma_f32_16x16x32_bf16(a1, b0, acc[1][0], 0, 0, 0);
            acc[1][1] = __builtin_amdgcn_mfma_f32_16x16x32_bf16(a1, b1, acc[1][1], 0, 0, 0);
        }
    }
#pragma unroll
    for (int i = 0; i < 2; ++i)
#pragma unroll
        for (int j = 0; j < 2; ++j) {
            const int col = n0 + wn + j * 16 + row16;
            const float bz = bias[col];
#pragma unroll
            for (int r = 0; r < 4; ++r) {
                const int rowm = m0 + wm + i * 16 + quad * 4 + r;
                float v = acc[i][j][r] + bz;
                if (relu) v = fmaxf(v, 0.f);
                C[(size_t)rowm * N + col] = (__bf16)v;
            }
        }
}

// ---------------------------------------------------------------------------
// K6: final 256-dot + bias + sigmoid (x2 bf16). One wave per batch row.
// ---------------------------------------------------------------------------
__global__ __launch_bounds__(256) void k_out(const __bf16* __restrict__ x2,
                                             const float* __restrict__ outW,
                                             const float* __restrict__ outb,
                                             float* __restrict__ out)
{
    const int t = threadIdx.x;
    const int wave = t >> 6, lane = t & 63;
    const int row = blockIdx.x * 4 + wave;
    bf16x4 xv = *(const bf16x4*)&x2[(size_t)row * 256 + lane * 4];
    const float4 wv = *(const float4*)&outW[lane * 4];
    float v = (float)xv[0] * wv.x + (float)xv[1] * wv.y
            + (float)xv[2] * wv.z + (float)xv[3] * wv.w;
    for (int off = 32; off; off >>= 1) v += __shfl_down(v, off);
    if (lane == 0) {
        float lg = v + outb[0];
        out[row] = 1.f / (1.f + expf(-lg));
        out[NB + row] = lg;
    }
}

// ---------------------------------------------------------------------------
extern "C" void kernel_launch(void* const* d_in, const int* in_sizes, int n_in,
                              void* d_out, int out_size, void* d_ws, size_t ws_size,
                              hipStream_t stream)
{
    const float* oh_tab = (const float*)d_in[0];
    const float* mh_tab = (const float*)d_in[1];
    const float* sp_tab = (const float*)d_in[2];
    const float* hw     = (const float*)d_in[3];
    const float* sqW = (const float*)d_in[4];  const float* sqb = (const float*)d_in[5];
    const float* skW = (const float*)d_in[6];  const float* skb = (const float*)d_in[7];
    const float* svW = (const float*)d_in[8];  const float* svb = (const float*)d_in[9];
    const float* soW = (const float*)d_in[10]; const float* sob = (const float*)d_in[11];
    const float* lqW = (const float*)d_in[12]; const float* lqb = (const float*)d_in[13];
    const float* lkW = (const float*)d_in[14]; const float* lkb = (const float*)d_in[15];
    const float* lvW = (const float*)d_in[16]; const float* lvb = (const float*)d_in[17];
    const float* loW = (const float*)d_in[18]; const float* lob = (const float*)d_in[19];
    const float* W0 = (const float*)d_in[20];  const float* b0 = (const float*)d_in[21];
    const float* W1 = (const float*)d_in[22];  const float* b1 = (const float*)d_in[23];
    const float* W2 = (const float*)d_in[24];  const float* b2 = (const float*)d_in[25];
    const float* outW = (const float*)d_in[26]; const float* outb = (const float*)d_in[27];
    const int* oh_ids = (const int*)d_in[28];
    const int* mh_ids = (const int*)d_in[29];
    const int* sp_ids = (const int*)d_in[30];
    (void)skb; (void)lkb;   // folded; per-head constant cancels in softmax

    // workspace layout (bytes, all 16B-aligned):
    char* ws = (char*)d_ws;
    unsigned int* sig = (unsigned int*)(ws + 0);            // 400128 * 4
    int*    sel   = (int*)   (ws + 1600512);                // 262144 * 4
    __bf16* feats = (__bf16*)(ws + 2649088);                // 884736 * 2
    __bf16* x0    = (__bf16*)(ws + 4418560);                // 524288 * 2
    __bf16* x1    = (__bf16*)(ws + 5467136);                // 262144 * 2
    __bf16* x2    = (__bf16*)(ws + 5991424);                // 131072 * 2
    __bf16* WT0   = (__bf16*)(ws + 6253568);                // 1769472 * 2
    __bf16* WT1   = (__bf16*)(ws + 9792512);                // 524288 * 2
    __bf16* WT2   = (__bf16*)(ws + 10841088);               // 131072 * 2
    float*  Mq    = (float*) (ws + 11103232);               // 131072 * 4
    float*  VO    = (float*) (ws + 11627520);               // 131072 * 4
    float*  B1    = (float*) (ws + 12151808);               // 2048 * 4
    float*  bvo   = (float*) (ws + 12160000);               // 512 * 4

    k_trans<<<dim3(1024 / 32, 1728 / 32), 256, 0, stream>>>(W0, WT0, 1728, 1024);
    k_trans<<<dim3(512 / 32, 1024 / 32), 256, 0, stream>>>(W1, WT1, 1024, 512);
    k_trans<<<dim3(256 / 32, 512 / 32), 256, 0, stream>>>(W2, WT2, 512, 256);
    k_fold<<<dim3(F_MH, 2, 4), 256, 0, stream>>>(sqW, sqb, skW, svW, svb, soW, sob,
                                                 lqW, lqb, lkW, lvW, lvb, loW, lob,
                                                 Mq, B1, VO, bvo);

    k_hash<<<(NROWS + 511) / 512, 128, 0, stream>>>(mh_tab, hw, sig);
    k_topk<<<dim3(NB, F_MH), 256, 0, stream>>>(oh_tab, hw, sig, oh_ids, mh_ids, sel);
    k_feats<<<NB, 256, 0, stream>>>(oh_tab, sp_tab, oh_ids, sp_ids, feats);
    k_attn<<<dim3(NB, F_MH, 2), 256, 0, stream>>>(oh_tab, mh_tab, oh_ids, mh_ids, sel,
                                                  Mq, B1, VO, bvo, feats);
    gemm_mfma<<<dim3(16, 8), 256, 0, stream>>>(feats, WT0, b0, x0, 512, 1024, 1728, 1);
    gemm_mfma<<<dim3(8, 8), 256, 0, stream>>>(x0, WT1, b1, x1, 512, 512, 1024, 1);
    gemm_mfma<<<dim3(4, 8), 256, 0, stream>>>(x1, WT2, b2, x2, 512, 256, 512, 1);
    k_out<<<NB / 4, 256, 0, stream>>>(x2, outW, outb, (float*)d_out);
}

// Round 7
// 418.918 us; speedup vs baseline: 1.1568x; 1.1568x over previous
//
#include <hip/hip_runtime.h>
#include <math.h>

#define F_MH 4
#define NB   512
#define SEQ  2048
#define TOPK 128
#define EDIM 64
#define ADIM 128
#define VOH  10001
#define VMH  100001
#define NROWS (F_MH * VMH)   // 400004
#define D0   1728
#define RSQRT32 0.17677669529663687f

typedef __bf16 bf16x8 __attribute__((ext_vector_type(8)));
typedef __bf16 bf16x4 __attribute__((ext_vector_type(4)));
typedef float  f32x4  __attribute__((ext_vector_type(4)));

// ---------------------------------------------------------------------------
// K1 (R6 rewrite): LSH signatures via bf16 hi/lo split MFMA.
// x = xh + xl, w = wh + wl (each split exact to ~2^-17 rel);
// acc = xh*wh + xh*wl + xl*wh  (drop xl*wl ~2^-18) -> rel err ~2^-16.
// Block 256 thr: 512 rows in 4 chunks of 128 (R4-style register prefetch,
// coalesced float4). Per chunk: 4 waves x 2 tiles of 16 rows; per tile
// 12x mfma_f32_16x16x32_bf16 (2 k-steps x 2 col-halves x 3 products).
// Sign bits assembled with __ballot (C-layout: col=lane&15, row=quad*4+reg
// -> each row's 16 col-bits are contiguous in the 64-bit mask).
// ---------------------------------------------------------------------------
__global__ __launch_bounds__(256) void k_hash(const float* __restrict__ tab,
                                              const float* __restrict__ hw,
                                              unsigned int* __restrict__ sig)
{
    __shared__ float rows[128][68];   // pitch 68: 16B-aligned b128, 2-way banks
    const int t = threadIdx.x;
    const int lane = t & 63, wave = t >> 6;
    const int m = lane & 15, quad = lane >> 4;

    // B fragments (hw hi/lo), loop-invariant. B[n][k]: n = hf*16+m, k = ks*32+quad*8+j
    bf16x8 whf[2][2], wlf[2][2];
#pragma unroll
    for (int ks = 0; ks < 2; ++ks)
#pragma unroll
        for (int hf = 0; hf < 2; ++hf) {
            bf16x8 bh, bl;
#pragma unroll
            for (int j = 0; j < 8; ++j) {
                const float w = hw[(ks * 32 + quad * 8 + j) * 32 + hf * 16 + m];
                const __bf16 h = (__bf16)w;
                bh[j] = h;
                bl[j] = (__bf16)(w - (float)h);
            }
            whf[ks][hf] = bh; wlf[ks][hf] = bl;
        }

    const long long base_dw = (long long)blockIdx.x * 32768;   // 512 rows * 64
    const long long lim = (long long)NROWS * 64;
    float4 pf[8];
#pragma unroll
    for (int i = 0; i < 8; ++i) {
        const long long idx = base_dw + i * 1024 + t * 4;
        pf[i] = make_float4(0.f, 0.f, 0.f, 0.f);
        if (idx < lim) pf[i] = *(const float4*)(tab + idx);
    }
    for (int c = 0; c < 4; ++c) {
        __syncthreads();              // prior chunk's LDS reads done
#pragma unroll
        for (int i = 0; i < 8; ++i) {
            const int v = t + i * 256;              // float4 index 0..2047
            *(float4*)&rows[v >> 4][(v & 15) << 2] = pf[i];
        }
        __syncthreads();
        if (c < 3) {                  // prefetch next chunk under compute
#pragma unroll
            for (int i = 0; i < 8; ++i) {
                const long long idx = base_dw + (long long)(c + 1) * 8192 + i * 1024 + t * 4;
                pf[i] = make_float4(0.f, 0.f, 0.f, 0.f);
                if (idx < lim) pf[i] = *(const float4*)(tab + idx);
            }
        }
#pragma unroll
        for (int tile = 0; tile < 2; ++tile) {
            const int rbase = wave * 32 + tile * 16;
            f32x4 acc0 = {0.f, 0.f, 0.f, 0.f}, acc1 = {0.f, 0.f, 0.f, 0.f};
#pragma unroll
            for (int ks = 0; ks < 2; ++ks) {
                const float* src = &rows[rbase + m][ks * 32 + quad * 8];
                const float4 x0 = *(const float4*)(src);
                const float4 x1 = *(const float4*)(src + 4);
                float xs[8] = {x0.x, x0.y, x0.z, x0.w, x1.x, x1.y, x1.z, x1.w};
                bf16x8 ah, al;
#pragma unroll
                for (int j = 0; j < 8; ++j) {
                    const __bf16 hx = (__bf16)xs[j];
                    ah[j] = hx;
                    al[j] = (__bf16)(xs[j] - (float)hx);
                }
                acc0 = __builtin_amdgcn_mfma_f32_16x16x32_bf16(ah, whf[ks][0], acc0, 0, 0, 0);
                acc0 = __builtin_amdgcn_mfma_f32_16x16x32_bf16(ah, wlf[ks][0], acc0, 0, 0, 0);
                acc0 = __builtin_amdgcn_mfma_f32_16x16x32_bf16(al, whf[ks][0], acc0, 0, 0, 0);
                acc1 = __builtin_amdgcn_mfma_f32_16x16x32_bf16(ah, whf[ks][1], acc1, 0, 0, 0);
                acc1 = __builtin_amdgcn_mfma_f32_16x16x32_bf16(ah, wlf[ks][1], acc1, 0, 0, 0);
                acc1 = __builtin_amdgcn_mfma_f32_16x16x32_bf16(al, whf[ks][1], acc1, 0, 0, 0);
            }
#pragma unroll
            for (int j = 0; j < 4; ++j) {
                const unsigned long long m0 = __ballot(acc0[j] > 0.f);
                const unsigned long long m1 = __ballot(acc1[j] > 0.f);
                if (m == 0) {
                    const unsigned int bits =
                        (unsigned int)((m0 >> (quad * 16)) & 0xFFFFull) |
                        ((unsigned int)((m1 >> (quad * 16)) & 0xFFFFull) << 16);
                    const long long gr = (long long)blockIdx.x * 512 + c * 128
                                       + rbase + quad * 4 + j;
                    if (gr < NROWS) sig[gr] = bits;
                }
            }
        }
    }
}

// ---------------------------------------------------------------------------
// K2: per-(f,b) top-K=128 by Hamming distance (histogram + stable tie pick).
// ---------------------------------------------------------------------------
__global__ __launch_bounds__(256) void k_topk(const float* __restrict__ oh_tab,
                                              const float* __restrict__ hw,
                                              const unsigned int* __restrict__ sig,
                                              const int* __restrict__ oh_ids,
                                              const int* __restrict__ mh_ids,
                                              int* __restrict__ sel)
{
    const int b = blockIdx.x, f = blockIdx.y, t = threadIdx.x;
    __shared__ float tgt[64];
    __shared__ unsigned int thbits;
    __shared__ int hist[34];
    __shared__ int c_lt[256], c_eq[256];
    __shared__ int s_dstar, s_cntlt;
    if (t < 64) tgt[t] = oh_tab[((size_t)f * VOH + oh_ids[b * 15 + f]) * 64 + t];
    if (t == 0) thbits = 0u;
    if (t < 34) hist[t] = 0;
    __syncthreads();
    if (t < 32) {
        float acc = 0.f;
#pragma unroll
        for (int e = 0; e < 64; ++e) acc += tgt[e] * hw[e * 32 + t];
        if (acc > 0.f) atomicOr(&thbits, 1u << t);
    }
    __syncthreads();
    const unsigned int th = thbits;
    const int* idp = mh_ids + (size_t)(f * NB + b) * SEQ + t * 8;
    int ids[8], dv[8];
#pragma unroll
    for (int j = 0; j < 8; ++j) {
        int id = idp[j];
        ids[j] = id;
        int d = (id >= 0) ? __popc(sig[f * VMH + id] ^ th) : 33;
        dv[j] = d;
        atomicAdd(&hist[d], 1);
    }
    __syncthreads();
    if (t == 0) {
        int cum = 0, ds = 33, cl = 0;
        for (int d = 0; d <= 33; ++d) {
            if (cum + hist[d] >= TOPK) { ds = d; cl = cum; break; }
            cum += hist[d];
        }
        s_dstar = ds; s_cntlt = cl;
    }
    __syncthreads();
    const int Dstar = s_dstar, cntlt = s_cntlt;
    int nlt = 0, neq = 0;
#pragma unroll
    for (int j = 0; j < 8; ++j) {
        nlt += (dv[j] < Dstar);
        neq += (dv[j] == Dstar);
    }
    c_lt[t] = nlt; c_eq[t] = neq;
    __syncthreads();
    for (int off = 1; off < 256; off <<= 1) {
        int vl = 0, ve = 0;
        if (t >= off) { vl = c_lt[t - off]; ve = c_eq[t - off]; }
        __syncthreads();
        c_lt[t] += vl; c_eq[t] += ve;
        __syncthreads();
    }
    int lt_pos = c_lt[t] - nlt;
    int eq_pos = cntlt + c_eq[t] - neq;
    int* selp = sel + (size_t)(f * NB + b) * TOPK;
#pragma unroll
    for (int j = 0; j < 8; ++j) {
        if (dv[j] < Dstar) { selp[lt_pos++] = ids[j]; }
        else if (dv[j] == Dstar) {
            if (eq_pos < TOPK) selp[eq_pos] = ids[j];
            eq_pos++;
        }
    }
}

// ---------------------------------------------------------------------------
// K_fold: precompute folded attention weights per (z,f,h).
// ---------------------------------------------------------------------------
__global__ __launch_bounds__(256) void k_fold(const float* __restrict__ sqW, const float* __restrict__ sqb,
                                              const float* __restrict__ skW,
                                              const float* __restrict__ svW, const float* __restrict__ svb,
                                              const float* __restrict__ soW, const float* __restrict__ sob,
                                              const float* __restrict__ lqW, const float* __restrict__ lqb,
                                              const float* __restrict__ lkW,
                                              const float* __restrict__ lvW, const float* __restrict__ lvb,
                                              const float* __restrict__ loW, const float* __restrict__ lob,
                                              float* __restrict__ Mq, float* __restrict__ B1,
                                              float* __restrict__ VO, float* __restrict__ bvo)
{
    const int f = blockIdx.x, z = blockIdx.y, h = blockIdx.z, t = threadIdx.x;
    const float* WQ = (z ? lqW : sqW) + (size_t)f * 8192;
    const float* bq = (z ? lqb : sqb) + f * 128;
    const float* WK = (z ? lkW : skW) + (size_t)f * 8192;
    const float* WV = (z ? lvW : svW) + (size_t)f * 8192;
    const float* bv = (z ? lvb : svb) + f * 128;
    const float* WO = (z ? loW : soW) + (size_t)f * 8192;
    const float* bo = (z ? lob : sob) + f * 64;

    __shared__ float wq[64][33], wk[64][33], wv[64][33], wo[32][65];
#pragma unroll
    for (int i = 0; i < 8; ++i) {
        int j = t + i * 256;
        wq[j >> 5][j & 31] = WQ[(j >> 5) * 128 + h * 32 + (j & 31)];
        wk[j >> 5][j & 31] = WK[(j >> 5) * 128 + h * 32 + (j & 31)];
        wv[j >> 5][j & 31] = WV[(j >> 5) * 128 + h * 32 + (j & 31)];
        wo[j >> 6][j & 63] = WO[(h * 32 + (j >> 6)) * 64 + (j & 63)];
    }
    __syncthreads();
    const int lane = t & 63, grp = t >> 6;
    float* Mqb = Mq + (size_t)(((z * 4 + f) * 4 + h)) * 4096;
    float* VOb = VO + (size_t)(((z * 4 + f) * 4 + h)) * 4096;
#pragma unroll 4
    for (int g = 0; g < 16; ++g) {
        const int ep = grp * 16 + g;
        float am = 0.f, av = 0.f;
#pragma unroll
        for (int d = 0; d < 32; ++d) {
            am += wq[ep][d] * wk[lane][d];
            av += wv[ep][d] * wo[d][lane];
        }
        Mqb[ep * 64 + lane] = am;
        VOb[ep * 64 + lane] = av;
    }
    if (t < 64) {
        float acc = 0.f;
#pragma unroll
        for (int d = 0; d < 32; ++d) acc += bq[h * 32 + d] * wk[t][d];
        B1[((z * 4 + f) * 4 + h) * 64 + t] = acc;
    }
    if (h == 0 && t >= 64 && t < 128) {
        const int o = t - 64;
        float acc = bo[o];
        for (int a = 0; a < 128; ++a) acc += bv[a] * WO[a * 64 + o];
        bvo[(z * 4 + f) * 64 + o] = acc;
    }
}

// ---------------------------------------------------------------------------
// K3: single-query attention via folded weights (R5 structure, kept).
// ---------------------------------------------------------------------------
__global__ __launch_bounds__(256, 4) void k_attn(const float* __restrict__ oh_tab,
                                                 const float* __restrict__ mh_tab,
                                                 const int* __restrict__ oh_ids,
                                                 const int* __restrict__ mh_ids,
                                                 const int* __restrict__ sel,
                                                 const float* __restrict__ Mq,
                                                 const float* __restrict__ B1,
                                                 const float* __restrict__ VO,
                                                 const float* __restrict__ bvo,
                                                 __bf16* __restrict__ feats)
{
    const int b = blockIdx.x, f = blockIdx.y, z = blockIdx.z, t = threadIdx.x;
    const int zf = z * 4 + f;
    const float* Mqb = Mq + (size_t)zf * 4 * 4096;
    const float* B1b = B1 + zf * 4 * 64;
    const float* VOb = VO + (size_t)zf * 4 * 4096;
    const float* bvob = bvo + zf * 64;

    __shared__ float seq[128][65];
    __shared__ float tgt[64];
    __shared__ int   sid[128];
    __shared__ float qk[4][64];
    __shared__ float sc[4][128];
    __shared__ float wemb[4][64];
    __shared__ float partial[4][64];

    if (t < 64) tgt[t] = oh_tab[((size_t)f * VOH + oh_ids[b * 15 + f]) * 64 + t];
    if (t < 128) {
        int id;
        if (z == 0) id = mh_ids[(size_t)(f * NB + b) * SEQ + t];
        else        id = sel[(size_t)(f * NB + b) * TOPK + t];
        sid[t] = id;
    }
    __syncthreads();
    float4 g[8];
#pragma unroll
    for (int i = 0; i < 8; ++i) {
        const int v = t + i * 256;
        const int row = v >> 4, c4 = (v & 15) << 2;
        const int id = sid[row];
        g[i] = make_float4(0.f, 0.f, 0.f, 0.f);
        if (id >= 0) g[i] = *(const float4*)&mh_tab[((size_t)f * VMH + id) * 64 + c4];
    }
    {
        const int h = t >> 6, e = t & 63;
        float acc = B1b[h * 64 + e];
        const float* mrow = Mqb + h * 4096 + e;
#pragma unroll 16
        for (int ep = 0; ep < 64; ++ep) acc += tgt[ep] * mrow[ep * 64];
        qk[h][e] = acc * RSQRT32;
    }
#pragma unroll
    for (int i = 0; i < 8; ++i) {
        const int v = t + i * 256;
        const int row = v >> 4, c4 = (v & 15) << 2;
        seq[row][c4 + 0] = g[i].x; seq[row][c4 + 1] = g[i].y;
        seq[row][c4 + 2] = g[i].z; seq[row][c4 + 3] = g[i].w;
    }
    __syncthreads();
#pragma unroll
    for (int rep = 0; rep < 2; ++rep) {
        const int idx = t + rep * 256;
        const int h = idx >> 7, s = idx & 127;
        float acc = 0.f;
#pragma unroll
        for (int e4 = 0; e4 < 16; ++e4) {
            const float4 q4 = *(const float4*)&qk[h][e4 * 4];
            acc += seq[s][e4 * 4 + 0] * q4.x + seq[s][e4 * 4 + 1] * q4.y
                 + seq[s][e4 * 4 + 2] * q4.z + seq[s][e4 * 4 + 3] * q4.w;
        }
        sc[h][s] = (sid[s] >= 0) ? acc : -INFINITY;
    }
    __syncthreads();
    {
        const int h = t >> 6, l = t & 63;
        float v0 = sc[h][l], v1 = sc[h][l + 64];
        float m = fmaxf(v0, v1);
        for (int off = 32; off; off >>= 1) m = fmaxf(m, __shfl_xor(m, off));
        float p0 = expf(v0 - m), p1 = expf(v1 - m);
        float ssum = p0 + p1;
        for (int off = 32; off; off >>= 1) ssum += __shfl_xor(ssum, off);
        float inv = 1.f / ssum;
        sc[h][l] = p0 * inv; sc[h][l + 64] = p1 * inv;
    }
    {
        const int h = t >> 6, e = t & 63;
        float acc = 0.f;
#pragma unroll 8
        for (int s4 = 0; s4 < 32; ++s4) {
            const float4 a4 = *(const float4*)&sc[h][s4 * 4];
            acc += a4.x * seq[s4 * 4 + 0][e] + a4.y * seq[s4 * 4 + 1][e]
                 + a4.z * seq[s4 * 4 + 2][e] + a4.w * seq[s4 * 4 + 3][e];
        }
        wemb[h][e] = acc;
    }
    {
        const int h = t >> 6, o = t & 63;
        float acc = 0.f;
        const float* vrow = VOb + h * 4096 + o;
#pragma unroll 16
        for (int e = 0; e < 64; ++e) acc += wemb[h][e] * vrow[e * 64];
        partial[h][o] = acc;
    }
    __syncthreads();
    if (t < 64) {
        float acc = partial[0][t] + partial[1][t] + partial[2][t] + partial[3][t] + bvob[t];
        feats[(size_t)b * D0 + (z ? 1472 : 1216) + f * 64 + t] = (__bf16)acc;
    }
}

// ---------------------------------------------------------------------------
// K4: feats assembly (bf16 output)
// ---------------------------------------------------------------------------
__global__ __launch_bounds__(256) void k_feats(const float* __restrict__ oh_tab,
                                               const float* __restrict__ sp_tab,
                                               const int* __restrict__ oh_ids,
                                               const int* __restrict__ sp_ids,
                                               __bf16* __restrict__ feats)
{
    const int b = blockIdx.x, t = threadIdx.x;
    __shared__ int sidl[200];
    __shared__ int ohid[15];
    if (t < 200) sidl[t] = sp_ids[(size_t)((t / 50) * NB + b) * 50 + (t % 50)];
    if (t >= 240 && t < 255) ohid[t - 240] = oh_ids[b * 15 + (t - 240)];
    __syncthreads();
    __bf16* fr = feats + (size_t)b * D0;
    for (int p = t; p < 960; p += 256) {
        int f = p >> 6, e = p & 63;
        fr[p] = (__bf16)oh_tab[((size_t)f * VOH + ohid[f]) * 64 + e];
    }
    {
        int f = t >> 6, e = t & 63;
        float acc = 0.f;
        for (int j = 0; j < 50; ++j) {
            int id = sidl[f * 50 + j];
            if (id >= 0) acc += sp_tab[((size_t)f * VOH + id) * 64 + e];
        }
        fr[960 + t] = (__bf16)acc;
    }
}

// ---------------------------------------------------------------------------
// K5a: weight transpose+convert: W f32 [K][N] -> WT bf16 [N][K]
// ---------------------------------------------------------------------------
__global__ __launch_bounds__(256) void k_trans(const float* __restrict__ W,
                                               __bf16* __restrict__ WT,
                                               int K, int N)
{
    __shared__ float tile[32][33];
    const int t = threadIdx.x;
    const int n0 = blockIdx.x * 32, k0 = blockIdx.y * 32;
    const int c = t & 31, r = t >> 5;
#pragma unroll
    for (int i = 0; i < 4; ++i)
        tile[r + 8 * i][c] = W[(size_t)(k0 + r + 8 * i) * N + n0 + c];
    __syncthreads();
#pragma unroll
    for (int i = 0; i < 4; ++i)
        WT[(size_t)(n0 + r + 8 * i) * K + k0 + c] = (__bf16)tile[c][r + 8 * i];
}

// ---------------------------------------------------------------------------
// K5b: bf16 MFMA GEMM. A [M,K] bf16 rm, BT [N,K] bf16 rm (pre-transposed),
// C = act(A@B + bias) as bf16 [M,N]. 64x64 tile, 4 waves = 2x2 of 32x32.
// ---------------------------------------------------------------------------
__global__ __launch_bounds__(256) void gemm_mfma(const __bf16* __restrict__ A,
                                                 const __bf16* __restrict__ BT,
                                                 const float* __restrict__ bias,
                                                 __bf16* __restrict__ C,
                                                 int M, int N, int K, int relu)
{
    __shared__ __bf16 As[64][72];
    __shared__ __bf16 Bs[64][72];
    const int t = threadIdx.x;
    const int n0 = blockIdx.x * 64, m0 = blockIdx.y * 64;
    const int wave = t >> 6, lane = t & 63;
    const int wm = (wave >> 1) * 32, wn = (wave & 1) * 32;
    const int row16 = lane & 15, quad = lane >> 4;
    f32x4 acc[2][2] = {};
    const int sr = t >> 3;
    const int sseg = (t & 7) * 8;
    for (int k0 = 0; k0 < K; k0 += 64) {
        bf16x8 av0 = *(const bf16x8*)&A[(size_t)(m0 + sr) * K + k0 + sseg];
        bf16x8 av1 = *(const bf16x8*)&A[(size_t)(m0 + sr + 32) * K + k0 + sseg];
        bf16x8 bv0 = *(const bf16x8*)&BT[(size_t)(n0 + sr) * K + k0 + sseg];
        bf16x8 bv1 = *(const bf16x8*)&BT[(size_t)(n0 + sr + 32) * K + k0 + sseg];
        __syncthreads();
        *(bf16x8*)&As[sr][sseg] = av0;
        *(bf16x8*)&As[sr + 32][sseg] = av1;
        *(bf16x8*)&Bs[sr][sseg] = bv0;
        *(bf16x8*)&Bs[sr + 32][sseg] = bv1;
        __syncthreads();
#pragma unroll
        for (int kk = 0; kk < 2; ++kk) {
            bf16x8 a0 = *(const bf16x8*)&As[wm + row16][kk * 32 + quad * 8];
            bf16x8 a1 = *(const bf16x8*)&As[wm + 16 + row16][kk * 32 + quad * 8];
            bf16x8 b0 = *(const bf16x8*)&Bs[wn + row16][kk * 32 + quad * 8];
            bf16x8 b1 = *(const bf16x8*)&Bs[wn + 16 + row16][kk * 32 + quad * 8];
            acc[0][0] = __builtin_amdgcn_mfma_f32_16x16x32_bf16(a0, b0, acc[0][0], 0, 0, 0);
            acc[0][1] = __builtin_amdgcn_mfma_f32_16x16x32_bf16(a0, b1, acc[0][1], 0, 0, 0);
            acc[1][0] = __builtin_amdgcn_mfma_f32_16x16x32_bf16(a1, b0, acc[1][0], 0, 0, 0);
            acc[1][1] = __builtin_amdgcn_mfma_f32_16x16x32_bf16(a1, b1, acc[1][1], 0, 0, 0);
        }
    }
#pragma unroll
    for (int i = 0; i < 2; ++i)
#pragma unroll
        for (int j = 0; j < 2; ++j) {
            const int col = n0 + wn + j * 16 + row16;
            const float bz = bias[col];
#pragma unroll
            for (int r = 0; r < 4; ++r) {
                const int rowm = m0 + wm + i * 16 + quad * 4 + r;
                float v = acc[i][j][r] + bz;
                if (relu) v = fmaxf(v, 0.f);
                C[(size_t)rowm * N + col] = (__bf16)v;
            }
        }
}

// ---------------------------------------------------------------------------
// K6: final 256-dot + bias + sigmoid (x2 bf16). One wave per batch row.
// ---------------------------------------------------------------------------
__global__ __launch_bounds__(256) void k_out(const __bf16* __restrict__ x2,
                                             const float* __restrict__ outW,
                                             const float* __restrict__ outb,
                                             float* __restrict__ out)
{
    const int t = threadIdx.x;
    const int wave = t >> 6, lane = t & 63;
    const int row = blockIdx.x * 4 + wave;
    bf16x4 xv = *(const bf16x4*)&x2[(size_t)row * 256 + lane * 4];
    const float4 wv = *(const float4*)&outW[lane * 4];
    float v = (float)xv[0] * wv.x + (float)xv[1] * wv.y
            + (float)xv[2] * wv.z + (float)xv[3] * wv.w;
    for (int off = 32; off; off >>= 1) v += __shfl_down(v, off);
    if (lane == 0) {
        float lg = v + outb[0];
        out[row] = 1.f / (1.f + expf(-lg));
        out[NB + row] = lg;
    }
}

// ---------------------------------------------------------------------------
extern "C" void kernel_launch(void* const* d_in, const int* in_sizes, int n_in,
                              void* d_out, int out_size, void* d_ws, size_t ws_size,
                              hipStream_t stream)
{
    const float* oh_tab = (const float*)d_in[0];
    const float* mh_tab = (const float*)d_in[1];
    const float* sp_tab = (const float*)d_in[2];
    const float* hw     = (const float*)d_in[3];
    const float* sqW = (const float*)d_in[4];  const float* sqb = (const float*)d_in[5];
    const float* skW = (const float*)d_in[6];  const float* skb = (const float*)d_in[7];
    const float* svW = (const float*)d_in[8];  const float* svb = (const float*)d_in[9];
    const float* soW = (const float*)d_in[10]; const float* sob = (const float*)d_in[11];
    const float* lqW = (const float*)d_in[12]; const float* lqb = (const float*)d_in[13];
    const float* lkW = (const float*)d_in[14]; const float* lkb = (const float*)d_in[15];
    const float* lvW = (const float*)d_in[16]; const float* lvb = (const float*)d_in[17];
    const float* loW = (const float*)d_in[18]; const float* lob = (const float*)d_in[19];
    const float* W0 = (const float*)d_in[20];  const float* b0 = (const float*)d_in[21];
    const float* W1 = (const float*)d_in[22];  const float* b1 = (const float*)d_in[23];
    const float* W2 = (const float*)d_in[24];  const float* b2 = (const float*)d_in[25];
    const float* outW = (const float*)d_in[26]; const float* outb = (const float*)d_in[27];
    const int* oh_ids = (const int*)d_in[28];
    const int* mh_ids = (const int*)d_in[29];
    const int* sp_ids = (const int*)d_in[30];
    (void)skb; (void)lkb;   // folded; per-head constant cancels in softmax

    char* ws = (char*)d_ws;
    unsigned int* sig = (unsigned int*)(ws + 0);            // 400128 * 4
    int*    sel   = (int*)   (ws + 1600512);                // 262144 * 4
    __bf16* feats = (__bf16*)(ws + 2649088);                // 884736 * 2
    __bf16* x0    = (__bf16*)(ws + 4418560);                // 524288 * 2
    __bf16* x1    = (__bf16*)(ws + 5467136);                // 262144 * 2
    __bf16* x2    = (__bf16*)(ws + 5991424);                // 131072 * 2
    __bf16* WT0   = (__bf16*)(ws + 6253568);                // 1769472 * 2
    __bf16* WT1   = (__bf16*)(ws + 9792512);                // 524288 * 2
    __bf16* WT2   = (__bf16*)(ws + 10841088);               // 131072 * 2
    float*  Mq    = (float*) (ws + 11103232);               // 131072 * 4
    float*  VO    = (float*) (ws + 11627520);               // 131072 * 4
    float*  B1    = (float*) (ws + 12151808);               // 2048 * 4
    float*  bvo   = (float*) (ws + 12160000);               // 512 * 4

    k_trans<<<dim3(1024 / 32, 1728 / 32), 256, 0, stream>>>(W0, WT0, 1728, 1024);
    k_trans<<<dim3(512 / 32, 1024 / 32), 256, 0, stream>>>(W1, WT1, 1024, 512);
    k_trans<<<dim3(256 / 32, 512 / 32), 256, 0, stream>>>(W2, WT2, 512, 256);
    k_fold<<<dim3(F_MH, 2, 4), 256, 0, stream>>>(sqW, sqb, skW, svW, svb, soW, sob,
                                                 lqW, lqb, lkW, lvW, lvb, loW, lob,
                                                 Mq, B1, VO, bvo);

    k_hash<<<(NROWS + 511) / 512, 256, 0, stream>>>(mh_tab, hw, sig);
    k_topk<<<dim3(NB, F_MH), 256, 0, stream>>>(oh_tab, hw, sig, oh_ids, mh_ids, sel);
    k_feats<<<NB, 256, 0, stream>>>(oh_tab, sp_tab, oh_ids, sp_ids, feats);
    k_attn<<<dim3(NB, F_MH, 2), 256, 0, stream>>>(oh_tab, mh_tab, oh_ids, mh_ids, sel,
                                                  Mq, B1, VO, bvo, feats);
    gemm_mfma<<<dim3(16, 8), 256, 0, stream>>>(feats, WT0, b0, x0, 512, 1024, 1728, 1);
    gemm_mfma<<<dim3(8, 8), 256, 0, stream>>>(x0, WT1, b1, x1, 512, 512, 1024, 1);
    gemm_mfma<<<dim3(4, 8), 256, 0, stream>>>(x1, WT2, b2, x2, 512, 256, 512, 1);
    k_out<<<NB / 4, 256, 0, stream>>>(x2, outW, outb, (float*)d_out);
}